// Round 1
// baseline (490.270 us; speedup 1.0000x reference)
//
#include <hip/hip_runtime.h>
#include <stdint.h>

#define E_EDGES 131072
#define NELEC 1024
#define NNUC 256
#define MAXCHUNK 256

typedef __attribute__((ext_vector_type(8))) short short8;
typedef __attribute__((ext_vector_type(4))) short short4_t;
typedef __attribute__((ext_vector_type(4))) float float4_t;

__device__ inline float silu_f(float x){ return x / (1.0f + expf(-x)); }

__device__ inline short f2bf_rne(float x){
    union { float f; uint32_t u; } a; a.f = x;
    return (short)((a.u + 0x7fffu + ((a.u >> 16) & 1u)) >> 16);
}
__device__ inline float bf2f(short h){
    union { uint32_t u; float f; } a; a.u = ((uint32_t)(uint16_t)h) << 16;
    return a.f;
}

// ---------------- h tables: h_all = silu(src_s @ W_h1) @ W_h2 ----------------
__global__ __launch_bounds__(192) void h_kernel(const float* __restrict__ s_elec,
                                                const float* __restrict__ s_nuc,
                                                const float* __restrict__ W_h1,
                                                const float* __restrict__ W_h2,
                                                float* __restrict__ h_out){
    int b = blockIdx.x; // 0..2303
    int t, node; const float* src; long hbase;
    if (b < NNUC)             { t = 0; node = b;               src = s_nuc;  hbase = 0; }
    else if (b < NNUC + NELEC){ t = 1; node = b - NNUC;        src = s_elec; hbase = (long)NNUC*192; }
    else                      { t = 2; node = b - NNUC - NELEC;src = s_elec; hbase = (long)NNUC*192 + (long)NELEC*192; }
    int tp = t + 1;
    __shared__ float s_row[64];
    __shared__ float hid[128];
    int j = threadIdx.x;
    if (j < 64) s_row[j] = src[node*64 + j];
    __syncthreads();
    if (j < 128){
        const float* w1 = W_h1 + (long)tp*64*128;
        float acc = 0.f;
        #pragma unroll
        for (int f = 0; f < 64; f++) acc += s_row[f] * w1[f*128 + j];
        hid[j] = silu_f(acc);
    }
    __syncthreads();
    {
        const float* w2 = W_h2 + (long)tp*128*192;
        float acc = 0.f;
        #pragma unroll
        for (int h = 0; h < 128; h++) acc += hid[h] * w2[h*192 + j];
        h_out[hbase + (long)node*192 + j] = acc;
    }
}

// ------------- pre-swizzle W_w into B-fragment order (hi/lo bf16) -------------
__global__ void wswizzle_kernel(const float* __restrict__ W_w,
                                short* __restrict__ fragH, short* __restrict__ fragL){
    int t = blockIdx.x; int tp = t + 1;
    const float* W = W_w + (long)tp*64*192;
    for (int idx = threadIdx.x; idx < 12*2*64*8; idx += blockDim.x){
        int j    = idx & 7;
        int lane = (idx >> 3) & 63;
        int ks   = (idx >> 9) & 1;
        int nt   = idx >> 10;
        int k = ks*32 + ((lane >> 4) & 3)*8 + j;
        int n = nt*16 + (lane & 15);
        float v = W[k*192 + n];
        short hi = f2bf_rne(v);
        short lo = f2bf_rne(v - bf2f(hi));
        fragH[t*12288 + idx] = hi;
        fragL[t*12288 + idx] = lo;
    }
}

// ---------------- CSR build ----------------
__global__ void hist_kernel(const int* __restrict__ receivers, int* __restrict__ counts){
    int gid = blockIdx.x * blockDim.x + threadIdx.x;
    if (gid >= 3*E_EDGES) return;
    int t = gid / E_EDGES, e = gid - t*E_EDGES;
    int r = receivers[(long)(t+1)*E_EDGES + e];
    atomicAdd(&counts[t*1024 + r], 1);
}

__global__ __launch_bounds__(1024) void scan_kernel(const int* __restrict__ counts,
                                                    int* __restrict__ offs, int* __restrict__ cursor){
    __shared__ int buf[1024];
    int tid = threadIdx.x;
    for (int t = 0; t < 3; t++){
        int v = counts[t*1024 + tid];
        buf[tid] = v;
        __syncthreads();
        int x = v;
        for (int off = 1; off < 1024; off <<= 1){
            int y = (tid >= off) ? buf[tid - off] : 0;
            __syncthreads();
            x += y; buf[tid] = x;
            __syncthreads();
        }
        int excl = x - v;
        offs[t*1024 + tid] = excl;
        cursor[t*1024 + tid] = excl;
        __syncthreads();
    }
}

__global__ void scatter_kernel(const int* __restrict__ receivers,
                               int* __restrict__ cursor, int* __restrict__ sorted_e){
    int gid = blockIdx.x * blockDim.x + threadIdx.x;
    if (gid >= 3*E_EDGES) return;
    int t = gid / E_EDGES, e = gid - t*E_EDGES;
    int r = receivers[(long)(t+1)*E_EDGES + e];
    int pos = atomicAdd(&cursor[t*1024 + r], 1);
    sorted_e[(long)t*E_EDGES + pos] = e;
}

// ---------------- output init: out = [s_elec | v_elec.reshape] ----------------
__global__ void out_init_kernel(const float* __restrict__ s_elec,
                                const float* __restrict__ v_elec, float* __restrict__ out){
    int gid = blockIdx.x * blockDim.x + threadIdx.x;
    if (gid >= NELEC*256) return;
    int n = gid >> 8, c = gid & 255;
    out[gid] = (c < 64) ? s_elec[n*64 + c] : v_elec[n*192 + (c - 64)];
}

// ---------------- main fused kernel: one block per (type, target) ----------------
__global__ __launch_bounds__(256) void main_kernel(
    const float* __restrict__ dist, const float* __restrict__ dirs,
    const float* __restrict__ v_elec, const float* __restrict__ v_nuc,
    const float* __restrict__ W_V, const float* __restrict__ W_U,
    const float* __restrict__ W_g1, const float* __restrict__ W_g2,
    const int* __restrict__ senders,
    const float* __restrict__ h_tab, const short* __restrict__ fragH, const short* __restrict__ fragL,
    const int* __restrict__ counts, const int* __restrict__ offs, const int* __restrict__ sorted_e,
    float* __restrict__ out)
{
    int b = blockIdx.x;
    int t = b >> 10;       // 0..2  (python type = t+1)
    int node = b & 1023;
    int tp = t + 1;
    const float* v_src = (t == 0) ? v_nuc : v_elec;
    long hbase = (t == 0) ? 0 : (t == 1 ? (long)NNUC*192 : (long)NNUC*192 + (long)NELEC*192);
    const float* hsrc = h_tab + hbase;

    int tid = threadIdx.x;
    int w = tid >> 6, l = tid & 63;
    int q = l >> 4, c16 = l & 15;
    int d = w*16 + c16;            // this lane's feature column (0..63)

    __shared__ short AH[2][64][8];
    __shared__ short AL[2][64][8];
    __shared__ int eid[MAXCHUNK];
    __shared__ int sid[MAXCHUNK];
    __shared__ float dls[16][3];
    __shared__ float zs[64];
    __shared__ float zv[64][3];
    __shared__ float VvL[192], UvL[192];
    __shared__ float gin[128], hidl[128], aL[192], vdotL[64];

    // ---- load pre-swizzled B fragments (W_w hi/lo) into registers ----
    short8 bh[3][2], bl[3][2];
    #pragma unroll
    for (int ni = 0; ni < 3; ni++){
        int nt = w + ni*4;   // ni=0: phi_s cols, ni=1: phi_vv, ni=2: phi_vs
        #pragma unroll
        for (int ks = 0; ks < 2; ks++){
            long base = (long)t*12288 + ((nt*2 + ks)*64 + l)*8;
            bh[ni][ks] = *(const short8*)(fragH + base);
            bl[ni][ks] = *(const short8*)(fragL + base);
        }
    }

    float acc_s = 0.f, acc_v0 = 0.f, acc_v1 = 0.f, acc_v2 = 0.f;

    int deg   = counts[t*1024 + node];
    int start = offs[t*1024 + node];

    for (int cbase = 0; cbase < deg || cbase == 0; cbase += MAXCHUNK){
        int chunk = deg - cbase; if (chunk > MAXCHUNK) chunk = MAXCHUNK; if (chunk < 0) chunk = 0;
        // stage edge ids + senders for this chunk
        {
            int i = tid;
            if (i < chunk){
                int e = sorted_e[(long)t*E_EDGES + start + cbase + i];
                eid[i] = e;
                sid[i] = senders[(long)tp*E_EDGES + e];
            } else { eid[i] = 0; sid[i] = 0; }
        }
        __syncthreads();
        int ngroups = (chunk + 15) >> 4;
        for (int g = 0; g < ngroups; g++){
            // ---- stage A: 16 dist rows -> hi/lo bf16 fragments in LDS ----
            {
                int m = tid >> 4;      // edge row 0..15
                int seg = tid & 15;    // k-chunk of 4
                int li = g*16 + m;
                float4_t dv = {0.f,0.f,0.f,0.f};
                int e = eid[li];
                if (li < chunk){
                    dv = *(const float4_t*)(dist + ((long)tp*E_EDGES + e)*64 + seg*4);
                }
                int ks   = seg >> 3;
                int quad = (seg >> 1) & 3;
                int j0   = (seg & 1)*4;
                int lane2 = m | (quad << 4);
                short4_t h4, l4;
                #pragma unroll
                for (int jj = 0; jj < 4; jj++){
                    short hi = f2bf_rne(dv[jj]);
                    h4[jj] = hi;
                    l4[jj] = f2bf_rne(dv[jj] - bf2f(hi));
                }
                *(short4_t*)&AH[ks][lane2][j0] = h4;
                *(short4_t*)&AL[ks][lane2][j0] = l4;
                if (tid < 48){
                    int mm = tid / 3, ii = tid - mm*3;
                    int li2 = g*16 + mm;
                    float dval = 0.f;
                    if (li2 < chunk) dval = dirs[((long)tp*E_EDGES + eid[li2])*3 + ii];
                    dls[mm][ii] = dval;
                }
            }
            __syncthreads();
            // ---- MFMA: we = dist @ W_w (split-bf16, 3 terms) ----
            short8 ah0 = *(short8*)&AH[0][l][0];
            short8 ah1 = *(short8*)&AH[1][l][0];
            short8 al0 = *(short8*)&AL[0][l][0];
            short8 al1 = *(short8*)&AL[1][l][0];
            float4_t C[3];
            #pragma unroll
            for (int ni = 0; ni < 3; ni++){
                float4_t acc = {0.f,0.f,0.f,0.f};
                acc = __builtin_amdgcn_mfma_f32_16x16x32_bf16(ah0, bh[ni][0], acc, 0, 0, 0);
                acc = __builtin_amdgcn_mfma_f32_16x16x32_bf16(ah1, bh[ni][1], acc, 0, 0, 0);
                acc = __builtin_amdgcn_mfma_f32_16x16x32_bf16(ah0, bl[ni][0], acc, 0, 0, 0);
                acc = __builtin_amdgcn_mfma_f32_16x16x32_bf16(ah1, bl[ni][1], acc, 0, 0, 0);
                acc = __builtin_amdgcn_mfma_f32_16x16x32_bf16(al0, bh[ni][0], acc, 0, 0, 0);
                acc = __builtin_amdgcn_mfma_f32_16x16x32_bf16(al1, bh[ni][1], acc, 0, 0, 0);
                C[ni] = acc;
            }
            // ---- epilogue: phi = we*hx; accumulate z_s, z_v ----
            #pragma unroll
            for (int reg = 0; reg < 4; reg++){
                int m = q*4 + reg;
                int s = sid[g*16 + m];
                const float* hp = hsrc + (long)s*192;
                acc_s += C[0][reg] * hp[d];
                float pvv = C[1][reg] * hp[64 + d];
                const float* vp = v_src + (long)s*192 + d*3;
                acc_v0 += pvv * vp[0];
                acc_v1 += pvv * vp[1];
                acc_v2 += pvv * vp[2];
                float pvs = C[2][reg] * hp[128 + d];
                acc_v0 += pvs * dls[m][0];
                acc_v1 += pvs * dls[m][1];
                acc_v2 += pvs * dls[m][2];
            }
            __syncthreads();
        }
        __syncthreads();
        if (deg == 0) break;
    }

    // ---- cross-quad reduction (rows of C live in different quads) ----
    acc_s  += __shfl_xor(acc_s, 16);  acc_s  += __shfl_xor(acc_s, 32);
    acc_v0 += __shfl_xor(acc_v0, 16); acc_v0 += __shfl_xor(acc_v0, 32);
    acc_v1 += __shfl_xor(acc_v1, 16); acc_v1 += __shfl_xor(acc_v1, 32);
    acc_v2 += __shfl_xor(acc_v2, 16); acc_v2 += __shfl_xor(acc_v2, 32);
    if (l < 16){
        zs[d] = acc_s;
        zv[d][0] = acc_v0; zv[d][1] = acc_v1; zv[d][2] = acc_v2;
    }
    __syncthreads();

    // ---- node update ----
    if (tid < 192){
        int i = tid >> 6, f = tid & 63;
        const float* wv = W_V + (long)tp*64*64;
        const float* wu = W_U + (long)tp*64*64;
        float av = 0.f, au = 0.f;
        #pragma unroll 8
        for (int dd = 0; dd < 64; dd++){
            float z = zv[dd][i];
            av += z * wv[dd*64 + f];
            au += z * wu[dd*64 + f];
        }
        VvL[f*3 + i] = av;
        UvL[f*3 + i] = au;
    }
    __syncthreads();
    if (tid < 64){
        int f = tid;
        float v0 = VvL[f*3], v1 = VvL[f*3+1], v2 = VvL[f*3+2];
        float u0 = UvL[f*3], u1 = UvL[f*3+1], u2 = UvL[f*3+2];
        gin[f] = zs[f];
        gin[64 + f] = v0*v0 + v1*v1 + v2*v2;
        vdotL[f] = u0*v0 + u1*v1 + u2*v2;
    }
    __syncthreads();
    if (tid < 128){
        const float* w1 = W_g1 + (long)tp*128*128;
        float acc = 0.f;
        #pragma unroll 8
        for (int c = 0; c < 128; c++) acc += gin[c] * w1[c*128 + tid];
        hidl[tid] = silu_f(acc);
    }
    __syncthreads();
    if (tid < 192){
        const float* w2 = W_g2 + (long)tp*128*192;
        float acc = 0.f;
        #pragma unroll 8
        for (int h = 0; h < 128; h++) acc += hidl[h] * w2[h*192 + tid];
        aL[tid] = acc;
    }
    __syncthreads();
    if (tid < 64){
        int f = tid;
        float upd = aL[128 + f] * vdotL[f] + aL[f];
        atomicAdd(&out[node*256 + f], upd);
    }
    if (tid < 192){
        int i = tid >> 6, f = tid & 63;
        float updv = UvL[f*3 + i] * aL[64 + f];
        atomicAdd(&out[node*256 + 64 + f*3 + i], updv);
    }
}

// ---------------- launcher ----------------
extern "C" void kernel_launch(void* const* d_in, const int* in_sizes, int n_in,
                              void* d_out, int out_size, void* d_ws, size_t ws_size,
                              hipStream_t stream){
    const float* s_elec  = (const float*)d_in[0];
    const float* v_elec  = (const float*)d_in[1];
    const float* s_nuc   = (const float*)d_in[2];
    const float* v_nuc   = (const float*)d_in[3];
    const float* dist    = (const float*)d_in[4];
    const float* dirs    = (const float*)d_in[5];
    const float* W_w     = (const float*)d_in[6];
    const float* W_h1    = (const float*)d_in[7];
    const float* W_h2    = (const float*)d_in[8];
    const float* W_g1    = (const float*)d_in[9];
    const float* W_g2    = (const float*)d_in[10];
    const float* W_V     = (const float*)d_in[11];
    const float* W_U     = (const float*)d_in[12];
    const int* senders   = (const int*)d_in[13];
    const int* receivers = (const int*)d_in[14];
    float* out = (float*)d_out;
    char* ws = (char*)d_ws;

    // workspace layout (bytes)
    float* h_tab    = (float*)(ws + 0);          // 442368 f32  = 1769472 B
    short* fragH    = (short*)(ws + 1769472);    // 36864 s16   = 73728 B
    short* fragL    = (short*)(ws + 1843200);    // 73728 B
    int*   counts   = (int*)  (ws + 1916928);    // 12288 B
    int*   offs     = (int*)  (ws + 1929216);    // 12288 B
    int*   cursor   = (int*)  (ws + 1941504);    // 12288 B
    int*   sorted_e = (int*)  (ws + 1953792);    // 1572864 B  -> total 3526656 B
    if (ws_size < 3526656) return;  // loud failure rather than memory corruption

    hipMemsetAsync(counts, 0, 3*1024*sizeof(int), stream);
    h_kernel<<<dim3(2304), dim3(192), 0, stream>>>(s_elec, s_nuc, W_h1, W_h2, h_tab);
    wswizzle_kernel<<<dim3(3), dim3(256), 0, stream>>>(W_w, fragH, fragL);
    hist_kernel<<<dim3(1536), dim3(256), 0, stream>>>(receivers, counts);
    scan_kernel<<<dim3(1), dim3(1024), 0, stream>>>(counts, offs, cursor);
    scatter_kernel<<<dim3(1536), dim3(256), 0, stream>>>(receivers, cursor, sorted_e);
    out_init_kernel<<<dim3(1024), dim3(256), 0, stream>>>(s_elec, v_elec, out);
    main_kernel<<<dim3(3072), dim3(256), 0, stream>>>(
        dist, dirs, v_elec, v_nuc, W_V, W_U, W_g1, W_g2, senders,
        h_tab, fragH, fragL, counts, offs, sorted_e, out);
}

// Round 2
// 371.855 us; speedup vs baseline: 1.3184x; 1.3184x over previous
//
#include <hip/hip_runtime.h>
#include <stdint.h>

#define E_EDGES 131072
#define NELEC 1024
#define NNUC 256
#define MAXCHUNK 256
#define NBLK 16          // hist/scatter blocks per type

typedef __attribute__((ext_vector_type(8))) short short8;
typedef __attribute__((ext_vector_type(4))) short short4_t;
typedef __attribute__((ext_vector_type(4))) float float4_t;
typedef __attribute__((ext_vector_type(4))) int int4_t;

__device__ inline float silu_f(float x){ return x / (1.0f + expf(-x)); }

__device__ inline short f2bf_rne(float x){
    union { float f; uint32_t u; } a; a.f = x;
    return (short)((a.u + 0x7fffu + ((a.u >> 16) & 1u)) >> 16);
}
__device__ inline float bf2f(short h){
    union { uint32_t u; float f; } a; a.u = ((uint32_t)(uint16_t)h) << 16;
    return a.f;
}

// ================= prep: h-table + W_w swizzle + out-init + histogram ========
// blocks: [0,288) h-table (8 nodes each) | [288,291) wswizzle | [291,547) out
//         [547,595) histogram
__global__ __launch_bounds__(256) void prep_kernel(
    const float* __restrict__ s_elec, const float* __restrict__ v_elec,
    const float* __restrict__ s_nuc,
    const float* __restrict__ W_h1, const float* __restrict__ W_h2,
    const float* __restrict__ W_w,
    const int* __restrict__ receivers,
    float* __restrict__ h_out, short* __restrict__ fragH, short* __restrict__ fragL,
    int* __restrict__ bh, float* __restrict__ out)
{
    int b = blockIdx.x, tid = threadIdx.x;
    __shared__ float sls[8][64];
    __shared__ float hidls[128][8];
    __shared__ int hist[1024];

    if (b < 288){
        // ---- h-table: h = silu(s @ W_h1) @ W_h2, 8 nodes/block ----
        int t, node0;
        if (b < 32){ t = 0; node0 = b*8; }
        else if (b < 160){ t = 1; node0 = (b-32)*8; }
        else { t = 2; node0 = (b-160)*8; }
        int tp = t + 1;
        const float* src = (t == 0) ? s_nuc : s_elec;
        long hbase = (t == 0) ? 0 : (t == 1 ? (long)NNUC*192 : (long)NNUC*192 + (long)NELEC*192);
        // stage 8 s-rows
        for (int i = tid; i < 512; i += 256){ int n = i >> 6, f = i & 63; sls[n][f] = src[(node0+n)*64 + f]; }
        __syncthreads();
        // layer 1: j = tid&127 over 128 hidden, nh = tid>>7 picks 4 nodes
        {
            int j = tid & 127, nh = tid >> 7;
            const float* w1 = W_h1 + (long)tp*64*128;
            float a0=0,a1=0,a2=0,a3=0;
            #pragma unroll 8
            for (int f = 0; f < 64; f++){
                float w = w1[f*128 + j];
                a0 += sls[nh*4+0][f]*w; a1 += sls[nh*4+1][f]*w;
                a2 += sls[nh*4+2][f]*w; a3 += sls[nh*4+3][f]*w;
            }
            float4_t hv = { silu_f(a0), silu_f(a1), silu_f(a2), silu_f(a3) };
            *(float4_t*)&hidls[j][nh*4] = hv;
        }
        __syncthreads();
        // layer 2: col = tid (<192), 8 nodes
        if (tid < 192){
            const float* w2 = W_h2 + (long)tp*128*192;
            float acc[8] = {0,0,0,0,0,0,0,0};
            #pragma unroll 4
            for (int h = 0; h < 128; h++){
                float w = w2[h*192 + tid];
                float4_t ha = *(float4_t*)&hidls[h][0];
                float4_t hb = *(float4_t*)&hidls[h][4];
                acc[0]+=ha[0]*w; acc[1]+=ha[1]*w; acc[2]+=ha[2]*w; acc[3]+=ha[3]*w;
                acc[4]+=hb[0]*w; acc[5]+=hb[1]*w; acc[6]+=hb[2]*w; acc[7]+=hb[3]*w;
            }
            #pragma unroll
            for (int n = 0; n < 8; n++) h_out[hbase + (long)(node0+n)*192 + tid] = acc[n];
        }
    } else if (b < 291){
        // ---- W_w swizzle into B-fragment order (hi/lo bf16) ----
        int t = b - 288, tp = t + 1;
        const float* W = W_w + (long)tp*64*192;
        for (int idx = tid; idx < 12288; idx += 256){
            int j    = idx & 7;
            int lane = (idx >> 3) & 63;
            int ks   = (idx >> 9) & 1;
            int nt   = idx >> 10;
            int k = ks*32 + ((lane >> 4) & 3)*8 + j;
            int n = nt*16 + (lane & 15);
            float v = W[k*192 + n];
            short hi = f2bf_rne(v);
            short lo = f2bf_rne(v - bf2f(hi));
            fragH[t*12288 + idx] = hi;
            fragL[t*12288 + idx] = lo;
        }
    } else if (b < 547){
        // ---- out init: [s_elec | v_elec] ----
        int i = (b - 291)*256 + tid;      // float4 index, 65536 total
        int n = i >> 6, c4 = i & 63;
        float4_t v;
        if (c4 < 16) v = *(const float4_t*)(s_elec + n*64 + c4*4);
        else         v = *(const float4_t*)(v_elec + n*192 + (c4-16)*4);
        *(float4_t*)(out + n*256 + c4*4) = v;
    } else {
        // ---- histogram: block (t, blk) over 8192 edges ----
        int hb = b - 547, t = hb >> 4, blk = hb & 15;
        for (int i = tid; i < 1024; i += 256) hist[i] = 0;
        __syncthreads();
        long base = (long)(t+1)*E_EDGES + blk*8192;
        #pragma unroll 4
        for (int it = 0; it < 32; it++){
            int r = receivers[base + it*256 + tid];
            atomicAdd(&hist[r], 1);
        }
        __syncthreads();
        for (int bin = tid; bin < 1024; bin += 256)
            bh[(t*1024 + bin)*NBLK + blk] = hist[bin];
    }
}

// ================= scan: exclusive scan of bh (49152), emit offs/counts ======
__global__ __launch_bounds__(1024) void scan_kernel(int* __restrict__ bh,
                                                    int* __restrict__ offs,
                                                    int* __restrict__ counts){
    __shared__ int buf[1024];
    int tid = threadIdx.x;
    int base = tid*48;
    int vals[48];
    const int4_t* p = (const int4_t*)(bh + base);
    int s = 0;
    #pragma unroll
    for (int j = 0; j < 12; j++){
        int4_t x = p[j];
        vals[j*4+0]=x[0]; vals[j*4+1]=x[1]; vals[j*4+2]=x[2]; vals[j*4+3]=x[3];
        s += x[0]+x[1]+x[2]+x[3];
    }
    buf[tid] = s;
    __syncthreads();
    int x = s;
    for (int off = 1; off < 1024; off <<= 1){
        int y = (tid >= off) ? buf[tid - off] : 0;
        __syncthreads();
        x += y; buf[tid] = x;
        __syncthreads();
    }
    int run = x - s;   // exclusive
    // 48 elements = exactly 3 (t,bin) groups of NBLK=16 each
    #pragma unroll
    for (int k = 0; k < 3; k++){
        int tb = tid*3 + k;
        offs[tb] = run;
        int c = 0;
        #pragma unroll
        for (int j = 0; j < 16; j++){
            int v = vals[k*16 + j];
            bh[base + k*16 + j] = run;
            run += v; c += v;
        }
        counts[tb] = c;
    }
}

// ================= scatter: LDS cursors, pack (sender<<17)|edge ==============
__global__ __launch_bounds__(256) void scatter_kernel(const int* __restrict__ receivers,
                                                      const int* __restrict__ senders,
                                                      const int* __restrict__ bh,
                                                      int* __restrict__ sorted){
    int hb = blockIdx.x, t = hb >> 4, blk = hb & 15;
    int tid = threadIdx.x;
    __shared__ int cur[1024];
    for (int bin = tid; bin < 1024; bin += 256) cur[bin] = bh[(t*1024 + bin)*NBLK + blk];
    __syncthreads();
    long base = (long)(t+1)*E_EDGES + blk*8192;
    #pragma unroll 2
    for (int it = 0; it < 32; it++){
        int e = blk*8192 + it*256 + tid;
        int r = receivers[base + it*256 + tid];
        int snd = senders[base + it*256 + tid];
        int pos = atomicAdd(&cur[r], 1);
        sorted[pos] = e | (snd << 17);
    }
}

// ================= main fused kernel: one block per (type, target) ===========
__global__ __launch_bounds__(256) void main_kernel(
    const float* __restrict__ dist, const float* __restrict__ dirs,
    const float* __restrict__ v_elec, const float* __restrict__ v_nuc,
    const float* __restrict__ W_V, const float* __restrict__ W_U,
    const float* __restrict__ W_g1, const float* __restrict__ W_g2,
    const float* __restrict__ h_tab, const short* __restrict__ fragH, const short* __restrict__ fragL,
    const int* __restrict__ counts, const int* __restrict__ offs, const int* __restrict__ sorted,
    float* __restrict__ out)
{
    int b = blockIdx.x;
    int t = b >> 10;
    int node = b & 1023;
    int tp = t + 1;
    const float* v_src = (t == 0) ? v_nuc : v_elec;
    long hbase = (t == 0) ? 0 : (t == 1 ? (long)NNUC*192 : (long)NNUC*192 + (long)NELEC*192);
    const float* hsrc = h_tab + hbase;

    int tid = threadIdx.x;
    int w = tid >> 6, l = tid & 63;
    int q = l >> 4, c16 = l & 15;
    int d = w*16 + c16;

    __shared__ short AH[2][2][64][8];   // [buf][ks][lane][j]
    __shared__ short AL[2][2][64][8];
    __shared__ float dls[2][16][3];
    __shared__ int eid[MAXCHUNK];
    __shared__ int sid[MAXCHUNK];
    __shared__ float zs[64];
    __shared__ float zv[64][3];
    __shared__ float VvL[192], UvL[192];
    __shared__ float gin[128], hidl[128], aL[192], vdotL[64];

    // B fragments (W_w hi/lo) in registers
    short8 bhf[3][2], blf[3][2];
    #pragma unroll
    for (int ni = 0; ni < 3; ni++){
        int nt = w + ni*4;
        #pragma unroll
        for (int ks = 0; ks < 2; ks++){
            long base = (long)t*12288 + ((nt*2 + ks)*64 + l)*8;
            bhf[ni][ks] = *(const short8*)(fragH + base);
            blf[ni][ks] = *(const short8*)(fragL + base);
        }
    }

    float acc_s = 0.f, acc_v0 = 0.f, acc_v1 = 0.f, acc_v2 = 0.f;

    int deg   = counts[t*1024 + node];
    int start = offs[t*1024 + node];

    int m = tid >> 4, seg = tid & 15;
    int ks_w = seg >> 3, quad_w = (seg >> 1) & 3, j0_w = (seg & 1)*4;
    int lane2 = m | (quad_w << 4);
    int mm = tid / 3, ii = tid - mm*3;   // dirs staging roles (tid<48)

    for (int cbase = 0; cbase < deg; cbase += MAXCHUNK){
        int chunk = deg - cbase; if (chunk > MAXCHUNK) chunk = MAXCHUNK;
        __syncthreads();   // protect eid/sid from previous chunk's readers
        {
            int v = 0;
            if (tid < chunk) v = sorted[(long)start + cbase + tid];
            eid[tid] = v & 131071;
            sid[tid] = v >> 17;
        }
        __syncthreads();

        int ngroups = (chunk + 15) >> 4;
        // prologue: load group 0
        float4_t dv = {0.f,0.f,0.f,0.f};
        if (m < chunk) dv = *(const float4_t*)(dist + ((long)tp*E_EDGES + eid[m])*64 + seg*4);
        float dirv = 0.f;
        if (tid < 48 && mm < chunk) dirv = dirs[((long)tp*E_EDGES + eid[mm])*3 + ii];

        for (int g = 0; g < ngroups; g++){
            int buf = g & 1;
            // write staged A (hi/lo bf16) + dirs
            {
                short4_t h4, l4;
                #pragma unroll
                for (int jj = 0; jj < 4; jj++){
                    short hi = f2bf_rne(dv[jj]);
                    h4[jj] = hi;
                    l4[jj] = f2bf_rne(dv[jj] - bf2f(hi));
                }
                *(short4_t*)&AH[buf][ks_w][lane2][j0_w] = h4;
                *(short4_t*)&AL[buf][ks_w][lane2][j0_w] = l4;
                if (tid < 48) dls[buf][mm][ii] = dirv;
            }
            // prefetch group g+1 (in flight across the barrier + compute)
            float4_t dvn = {0.f,0.f,0.f,0.f};
            float dirn = 0.f;
            if (g + 1 < ngroups){
                int li = (g+1)*16 + m;
                if (li < chunk) dvn = *(const float4_t*)(dist + ((long)tp*E_EDGES + eid[li])*64 + seg*4);
                int li2 = (g+1)*16 + mm;
                if (tid < 48 && li2 < chunk) dirn = dirs[((long)tp*E_EDGES + eid[li2])*3 + ii];
            }
            __syncthreads();

            // gather h/v early (independent of MFMA)
            int sA[4];
            float hg[4][3], vg[4][3];
            #pragma unroll
            for (int reg = 0; reg < 4; reg++){
                int mr = q*4 + reg;
                int s = sid[g*16 + mr];
                sA[reg] = mr;
                const float* hp = hsrc + (long)s*192;
                hg[reg][0] = hp[d]; hg[reg][1] = hp[64 + d]; hg[reg][2] = hp[128 + d];
                const float* vp = v_src + (long)s*192 + d*3;
                vg[reg][0] = vp[0]; vg[reg][1] = vp[1]; vg[reg][2] = vp[2];
            }

            // MFMA: we = dist @ W_w, split-bf16 3-term
            short8 ah0 = *(short8*)&AH[buf][0][l][0];
            short8 ah1 = *(short8*)&AH[buf][1][l][0];
            short8 al0 = *(short8*)&AL[buf][0][l][0];
            short8 al1 = *(short8*)&AL[buf][1][l][0];
            float4_t C[3];
            #pragma unroll
            for (int ni = 0; ni < 3; ni++){
                float4_t acc = {0.f,0.f,0.f,0.f};
                acc = __builtin_amdgcn_mfma_f32_16x16x32_bf16(ah0, bhf[ni][0], acc, 0, 0, 0);
                acc = __builtin_amdgcn_mfma_f32_16x16x32_bf16(ah1, bhf[ni][1], acc, 0, 0, 0);
                acc = __builtin_amdgcn_mfma_f32_16x16x32_bf16(ah0, blf[ni][0], acc, 0, 0, 0);
                acc = __builtin_amdgcn_mfma_f32_16x16x32_bf16(ah1, blf[ni][1], acc, 0, 0, 0);
                acc = __builtin_amdgcn_mfma_f32_16x16x32_bf16(al0, bhf[ni][0], acc, 0, 0, 0);
                acc = __builtin_amdgcn_mfma_f32_16x16x32_bf16(al1, bhf[ni][1], acc, 0, 0, 0);
                C[ni] = acc;
            }
            // combine
            #pragma unroll
            for (int reg = 0; reg < 4; reg++){
                int mr = sA[reg];
                acc_s += C[0][reg] * hg[reg][0];
                float pvv = C[1][reg] * hg[reg][1];
                acc_v0 += pvv * vg[reg][0];
                acc_v1 += pvv * vg[reg][1];
                acc_v2 += pvv * vg[reg][2];
                float pvs = C[2][reg] * hg[reg][2];
                acc_v0 += pvs * dls[buf][mr][0];
                acc_v1 += pvs * dls[buf][mr][1];
                acc_v2 += pvs * dls[buf][mr][2];
            }
            dv = dvn; dirv = dirn;
        }
    }

    // cross-quad reduction
    acc_s  += __shfl_xor(acc_s, 16);  acc_s  += __shfl_xor(acc_s, 32);
    acc_v0 += __shfl_xor(acc_v0, 16); acc_v0 += __shfl_xor(acc_v0, 32);
    acc_v1 += __shfl_xor(acc_v1, 16); acc_v1 += __shfl_xor(acc_v1, 32);
    acc_v2 += __shfl_xor(acc_v2, 16); acc_v2 += __shfl_xor(acc_v2, 32);
    __syncthreads();   // all waves done with A buffers; reuse LDS below
    if (l < 16){
        zs[d] = acc_s;
        zv[d][0] = acc_v0; zv[d][1] = acc_v1; zv[d][2] = acc_v2;
    }
    __syncthreads();

    // node update
    if (tid < 192){
        int i = tid >> 6, f = tid & 63;
        const float* wv = W_V + (long)tp*64*64;
        const float* wu = W_U + (long)tp*64*64;
        float av = 0.f, au = 0.f;
        #pragma unroll 8
        for (int dd = 0; dd < 64; dd++){
            float z = zv[dd][i];
            av += z * wv[dd*64 + f];
            au += z * wu[dd*64 + f];
        }
        VvL[f*3 + i] = av;
        UvL[f*3 + i] = au;
    }
    __syncthreads();
    if (tid < 64){
        int f = tid;
        float v0 = VvL[f*3], v1 = VvL[f*3+1], v2 = VvL[f*3+2];
        float u0 = UvL[f*3], u1 = UvL[f*3+1], u2 = UvL[f*3+2];
        gin[f] = zs[f];
        gin[64 + f] = v0*v0 + v1*v1 + v2*v2;
        vdotL[f] = u0*v0 + u1*v1 + u2*v2;
    }
    __syncthreads();
    if (tid < 128){
        const float* w1 = W_g1 + (long)tp*128*128;
        float acc = 0.f;
        #pragma unroll 8
        for (int c = 0; c < 128; c++) acc += gin[c] * w1[c*128 + tid];
        hidl[tid] = silu_f(acc);
    }
    __syncthreads();
    if (tid < 192){
        const float* w2 = W_g2 + (long)tp*128*192;
        float acc = 0.f;
        #pragma unroll 8
        for (int h = 0; h < 128; h++) acc += hidl[h] * w2[h*192 + tid];
        aL[tid] = acc;
    }
    __syncthreads();
    if (tid < 64){
        int f = tid;
        float upd = aL[128 + f] * vdotL[f] + aL[f];
        atomicAdd(&out[node*256 + f], upd);
    }
    if (tid < 192){
        int i = tid >> 6, f = tid & 63;
        float updv = UvL[f*3 + i] * aL[64 + f];
        atomicAdd(&out[node*256 + 64 + f*3 + i], updv);
    }
}

// ================= launcher ==================================================
extern "C" void kernel_launch(void* const* d_in, const int* in_sizes, int n_in,
                              void* d_out, int out_size, void* d_ws, size_t ws_size,
                              hipStream_t stream){
    const float* s_elec  = (const float*)d_in[0];
    const float* v_elec  = (const float*)d_in[1];
    const float* s_nuc   = (const float*)d_in[2];
    const float* v_nuc   = (const float*)d_in[3];
    const float* dist    = (const float*)d_in[4];
    const float* dirs    = (const float*)d_in[5];
    const float* W_w     = (const float*)d_in[6];
    const float* W_h1    = (const float*)d_in[7];
    const float* W_h2    = (const float*)d_in[8];
    const float* W_g1    = (const float*)d_in[9];
    const float* W_g2    = (const float*)d_in[10];
    const float* W_V     = (const float*)d_in[11];
    const float* W_U     = (const float*)d_in[12];
    const int* senders   = (const int*)d_in[13];
    const int* receivers = (const int*)d_in[14];
    float* out = (float*)d_out;
    char* ws = (char*)d_ws;

    // workspace layout (bytes)
    float* h_tab  = (float*)(ws + 0);          // 1769472 B
    short* fragH  = (short*)(ws + 1769472);    // 73728 B
    short* fragL  = (short*)(ws + 1843200);    // 73728 B
    int*   bh     = (int*)  (ws + 1916928);    // 196608 B
    int*   offs   = (int*)  (ws + 2113536);    // 12288 B
    int*   counts = (int*)  (ws + 2125824);    // 12288 B
    int*   sorted = (int*)  (ws + 2138112);    // 1572864 B -> end 3710976
    if (ws_size < 3710976) return;

    prep_kernel<<<dim3(595), dim3(256), 0, stream>>>(
        s_elec, v_elec, s_nuc, W_h1, W_h2, W_w, receivers,
        h_tab, fragH, fragL, bh, out);
    scan_kernel<<<dim3(1), dim3(1024), 0, stream>>>(bh, offs, counts);
    scatter_kernel<<<dim3(48), dim3(256), 0, stream>>>(receivers, senders, bh, sorted);
    main_kernel<<<dim3(3072), dim3(256), 0, stream>>>(
        dist, dirs, v_elec, v_nuc, W_V, W_U, W_g1, W_g2,
        h_tab, fragH, fragL, counts, offs, sorted, out);
}